// Round 12
// baseline (5711.624 us; speedup 1.0000x reference)
//
#include <hip/hip_runtime.h>
#include <hip/hip_bf16.h>
#include <math.h>

// Problem constants
#define N_B    256   // batch
#define L_SEQ  512   // sequence length
#define HID    512   // hidden
#define EMB_D  256   // embedding dim

// 16 groups x 16 batch rows; 8 wgs/group each owning 64 Whh cols (hi/lo bf16
// frags in registers; 1.5 MB aggregate requires >=8 CUs/group).
#define NGROUPS 16
#define GWGS    8

// Workspace: E_sw + exchange (parity dbuf). Exchange words self-validate via
// an epoch tag in bit16 (lo-plane LSB) — no flags, no drains (R11-proven).
#define ESW_SHORTS_PER_BLK 8192   // per (g,t): 2 planes x 8 kk x 64 lanes x 8 = 16 KB
#define ESW_BYTES  ((size_t)NGROUPS * L_SEQ * ESW_SHORTS_PER_BLK * 2)  // 134,217,728
#define EX_UINTS_PER_SLOT (16 * HID)                                   // 8192 = 32 KB
#define EX_BYTES   ((size_t)2 * NGROUPS * EX_UINTS_PER_SLOT * 4)       // 1 MB

typedef short v8s __attribute__((ext_vector_type(8)));   // 8 bf16 MFMA A/B frag
typedef float v4f __attribute__((ext_vector_type(4)));   // MFMA C/D frag

static __device__ __forceinline__ unsigned short bf_bits(__hip_bfloat16 h) {
    union { __hip_bfloat16 b; unsigned short u; } c; c.b = h; return c.u;
}
static __device__ __forceinline__ void split_hilo(float v, short& hi, short& lo) {
    const __hip_bfloat16 h = __float2bfloat16(v);
    hi = (short)bf_bits(h);
    lo = (short)bf_bits(__float2bfloat16(v - __bfloat162float(h)));
}
static __device__ __forceinline__ void cvt8_hilo(const float* __restrict__ p,
                                                 v8s& hi, v8s& lo) {
    #pragma unroll
    for (int i = 0; i < 8; ++i) { short h, l; split_hilo(p[i], h, l); hi[i] = h; lo[i] = l; }
}
// fast tanh: 1 - 2/(exp(2x)+1); v_exp_f32-based, ~1e-7 abs err
static __device__ __forceinline__ float tanh_fast(float x) {
    const float z = __expf(2.0f * x);
    return 1.0f - 2.0f / (z + 1.0f);
}

// ---------------------------------------------------------------------------
// Precompute E_sw (unchanged, correctness-proven): per (g,t) the 16 emb rows
// split hi/lo, MFMA A-frag order:
//   short off = plane*4096 + (kk*64 + lane)*8 + i,  lane = m + 16*q',
//   element = emb[X[g*16+m][t]][kk*32 + q'*8 + i]
// ---------------------------------------------------------------------------
__global__ __launch_bounds__(256) void esw_build(
    const int* __restrict__ X, const float* __restrict__ emb,
    short* __restrict__ Esw)
{
    const int bid = blockIdx.x;           // g*512 + t
    const int g = bid >> 9, t = bid & 511;
    short* base = Esw + (size_t)bid * ESW_SHORTS_PER_BLK;
    #pragma unroll
    for (int h = 0; h < 2; ++h) {
        const int f    = threadIdx.x + h * 256;   // frag id 0..511
        const int kk   = f >> 6, lane = f & 63;
        const int m    = lane & 15, qp = lane >> 4;
        const int idx  = X[(g * 16 + m) * L_SEQ + t];
        const float* src = emb + (size_t)idx * EMB_D + kk * 32 + qp * 8;
        v8s hi8, lo8;
        cvt8_hilo(src, hi8, lo8);
        short* d = base + (size_t)(kk * 64 + lane) * 8;
        *(v8s*)d          = hi8;
        *(v8s*)(d + 4096) = lo8;
    }
}

// ---------------------------------------------------------------------------
// Persistent RNN scan, REGISTERS-DIRECT, ZERO BARRIERS. 128 wgs = 16 groups
// x 8 members, 256 thr (4 waves), but waves are fully independent: since the
// exchange and Esw are both in A-frag order and every wave needs identical
// A-frags, each wave loads h straight from L3 into VGPRs (64 u64 sc1 loads,
// seqlock tag-poll = the transfer itself), unpacks in-register (~2 ops/word),
// and MFMAs. E frags are 16 regular dwordx4 loads from Esw. No h-LDS staging,
// no global_load_lds, NO __syncthreads in the whole kernel body (R11's
// barrier re-coupled all 4 waves to the slowest every step). LDS = 4 KB
// publish-transpose scratch only (intra-wave, in-order DS pipe).
// Tag check: AND/OR-reduce over all 64 u64s (validates every word's epoch
// bit — no line-atomicity assumption). WAR-at-distance-2 (per-wave): wave's
// poll(t) success <= all 32 producer-waves published(t-1) <= each finished
// its reads of buffer[P^1] at step t-1 before publishing.
// ---------------------------------------------------------------------------
__global__ __launch_bounds__(256, 1) void rnn_scan6(
    const float* __restrict__ Whh,
    const float* __restrict__ Whh_b,
    const float* __restrict__ Wxh,
    const float* __restrict__ Wxh_b,
    const short* __restrict__ Esw,
    unsigned int* __restrict__ ex,
    float* __restrict__ out)
{
    const int bid  = blockIdx.x;
    const int g    = bid & 15;    // group (members share XCD via %8 heuristic)
    const int j    = bid >> 4;    // member 0..7
    const int tid  = threadIdx.x;
    const int w    = tid >> 6;
    const int l    = tid & 63;
    const int lo16 = l & 15;
    const int q    = l >> 4;
    const int cbase = j * 64 + w * 16;
    const int nbase = g * 16;

    __shared__ unsigned int tp[4][256];   // per-wave publish transpose scratch

    // Whh 64-col slice as hi/lo bf16 B-frags (128 VGPRs)
    v8s bhi[16], blo[16];
    {
        const float* wp = Whh + (long)(cbase + lo16) * HID + q * 8;
        #pragma unroll
        for (int kk = 0; kk < 16; ++kk) cvt8_hilo(wp + kk * 32, bhi[kk], blo[kk]);
    }
    // Wxh 64-col slice (64 VGPRs)
    v8s xhi[8], xlo[8];
    {
        const float* wp = Wxh + (long)(cbase + lo16) * EMB_D + q * 8;
        #pragma unroll
        for (int kk = 0; kk < 8; ++kk) cvt8_hilo(wp + kk * 32, xhi[kk], xlo[kk]);
    }
    const int hcol = cbase + lo16;
    const float bias = Whh_b[hcol] + Wxh_b[hcol];

    // wave's contiguous 1 KB publish region (uints): kk_s = 2j + (w>>1),
    // covering q2 = 2(w&1)..2(w&1)+1.
    const int region = (2 * j + (w >> 1)) * 512 + (w & 1) * 256;

    unsigned int* ex0 = ex + (size_t)g * EX_UINTS_PER_SLOT;              // parity 0
    unsigned int* ex1 = ex + (size_t)(NGROUPS + g) * EX_UINTS_PER_SLOT;  // parity 1
    const short* esrc = Esw + (size_t)(g * 512) * ESW_SHORTS_PER_BLK;

    for (int t = 0; t < L_SEQ; ++t) {
        const int P = t & 1;
        const unsigned long long* exsrc =
            (const unsigned long long*)(P ? ex1 : ex0);
        unsigned int* exdst = P ? ex0 : ex1;

        // (1) E frags: 16 regular dwordx4 from Esw (read-only, L2-cacheable),
        //     then 24 E MFMAs — fills the slack while peers' h propagates.
        v4f acc0 = {0,0,0,0}, acc1 = {0,0,0,0}, acc2 = {0,0,0,0};
        {
            const short* eb = esrc + (size_t)t * ESW_SHORTS_PER_BLK;
            #pragma unroll
            for (int kk = 0; kk < 8; ++kk) {
                v8s ah = *(const v8s*)(eb + (kk * 64 + l) * 8);
                v8s al = *(const v8s*)(eb + 4096 + (kk * 64 + l) * 8);
                acc0 = __builtin_amdgcn_mfma_f32_16x16x32_bf16(ah, xhi[kk], acc0, 0, 0, 0);
                acc1 = __builtin_amdgcn_mfma_f32_16x16x32_bf16(ah, xlo[kk], acc1, 0, 0, 0);
                acc2 = __builtin_amdgcn_mfma_f32_16x16x32_bf16(al, xhi[kk], acc2, 0, 0, 0);
            }
        }

        // (2) seqlock poll: 64 u64 sc1 loads (whole slot, this lane's frag
        //     words: u64 idx = kk*256 + l*4 + ii), AND/OR-reduced tag check.
        unsigned long long hv[64];
        {
            const unsigned long long M = 0x0001000000010000ull;
            const int want1 = (t >> 1) & 1;
            bool pass;
            do {
                #pragma unroll
                for (int kk = 0; kk < 16; ++kk)
                    #pragma unroll
                    for (int ii = 0; ii < 4; ++ii)
                        hv[kk * 4 + ii] = __hip_atomic_load(
                            exsrc + kk * 256 + l * 4 + ii,
                            __ATOMIC_RELAXED, __HIP_MEMORY_SCOPE_AGENT);
                if (want1) {
                    unsigned long long a = ~0ull;
                    #pragma unroll
                    for (int s = 0; s < 64; ++s) a &= hv[s];
                    pass = ((a & M) == M);
                } else {
                    unsigned long long a = 0ull;
                    #pragma unroll
                    for (int s = 0; s < 64; ++s) a |= hv[s];
                    pass = ((a & M) == 0ull);
                }
            } while (!__all(pass));
        }

        // (3) unpack in-register + 48 h MFMAs (packed word = hi | lo<<16)
        #pragma unroll
        for (int kk = 0; kk < 16; ++kk) {
            union { v8s s; unsigned int u[4]; } ah, al;
            #pragma unroll
            for (int ii = 0; ii < 4; ++ii) {
                const unsigned long long v = hv[kk * 4 + ii];
                const unsigned int w0 = (unsigned int)v;
                const unsigned int w1 = (unsigned int)(v >> 32);
                ah.u[ii] = (w0 & 0xffffu) | (w1 << 16);
                al.u[ii] = (w0 >> 16)     | (w1 & 0xffff0000u);
            }
            acc0 = __builtin_amdgcn_mfma_f32_16x16x32_bf16(ah.s, bhi[kk], acc0, 0, 0, 0);
            acc1 = __builtin_amdgcn_mfma_f32_16x16x32_bf16(ah.s, blo[kk], acc1, 0, 0, 0);
            acc2 = __builtin_amdgcn_mfma_f32_16x16x32_bf16(al.s, bhi[kk], acc2, 0, 0, 0);
        }

        // (4) epilogue: tanh, split, tag bit16, transpose via wave-local LDS,
        //     4 fully coalesced sc1 stores. No drain, no flag, no barrier.
        if (t < L_SEQ - 1) {
            const unsigned int wtag = (unsigned int)(((t + 1) >> 1) & 1) << 16;
            unsigned int* myt = tp[w];
            #pragma unroll
            for (int r = 0; r < 4; ++r) {
                const int m = q * 4 + r;             // C/D: row=(lane>>4)*4+r
                const float pre = acc0[r] + acc1[r] + acc2[r] + bias;
                const float hv2 = tanh_fast(pre);
                short hi, lo; split_hilo(hv2, hi, lo);
                unsigned int word = (unsigned int)(unsigned short)hi
                                  | ((unsigned int)(unsigned short)lo << 16);
                word = (word & 0xFFFEFFFFu) | wtag;   // lo-LSB := epoch tag
                myt[(m + 16 * (lo16 >> 3)) * 8 + (lo16 & 7)] = word;
            }
            asm volatile("s_waitcnt lgkmcnt(0)" ::: "memory");
            #pragma unroll
            for (int k = 0; k < 4; ++k) {
                const unsigned int val = myt[k * 64 + l];
                __hip_atomic_store(exdst + region + k * 64 + l, val,
                                   __ATOMIC_RELAXED, __HIP_MEMORY_SCOPE_AGENT);
            }
        } else {
            #pragma unroll
            for (int r = 0; r < 4; ++r) {
                const int m = q * 4 + r;
                const float pre = acc0[r] + acc1[r] + acc2[r] + bias;
                out[(long)(nbase + m) * HID + hcol] = tanh_fast(pre);
            }
        }
    }
}

// ---------------------------------------------------------------------------
extern "C" void kernel_launch(void* const* d_in, const int* in_sizes, int n_in,
                              void* d_out, int out_size, void* d_ws, size_t ws_size,
                              hipStream_t stream) {
    const int*   X     = (const int*)d_in[0];
    const float* emb   = (const float*)d_in[1];
    const float* Whh   = (const float*)d_in[2];
    const float* Whh_b = (const float*)d_in[3];
    const float* Wxh   = (const float*)d_in[4];
    const float* Wxh_b = (const float*)d_in[5];

    char* ws = (char*)d_ws;
    short*        Esw = (short*)ws;
    unsigned int* ex  = (unsigned int*)(ws + ESW_BYTES);

    // parity 0 := 0x00 (h(0)=0, tag 0 matches t=0 immediately);
    // parity 1 := 0xFF (tag 1 blocks t=1 until step-0 data lands).
    hipMemsetAsync(ex, 0x00, EX_BYTES / 2, stream);
    hipMemsetAsync((char*)ex + EX_BYTES / 2, 0xFF, EX_BYTES / 2, stream);

    esw_build<<<dim3(NGROUPS * L_SEQ), dim3(256), 0, stream>>>(X, emb, Esw);
    rnn_scan6<<<dim3(NGROUPS * GWGS), dim3(256), 0, stream>>>(
        Whh, Whh_b, Wxh, Wxh_b, Esw, ex, (float*)d_out);
}

// Round 13
// 2061.149 us; speedup vs baseline: 2.7711x; 2.7711x over previous
//
#include <hip/hip_runtime.h>
#include <hip/hip_bf16.h>
#include <math.h>

// Problem constants
#define N_B    256   // batch
#define L_SEQ  512   // sequence length
#define HID    512   // hidden
#define EMB_D  256   // embedding dim

// 16 groups x 16 batch rows; 8 wgs/group each owning 64 Whh cols (hi/lo bf16
// frags in registers; 1.5 MB aggregate requires >=8 CUs/group).
#define NGROUPS 16
#define GWGS    8

// Workspace: E_sw + exchange (parity dbuf) + xcd-id scratch. Exchange words
// self-validate via epoch tag in bit16 (lo-plane LSB) — R11-proven seqlock.
#define ESW_SHORTS_PER_BLK 8192   // per (g,t): 2 planes x 8 kk x 64 lanes x 8 = 16 KB
#define ESW_BYTES  ((size_t)NGROUPS * L_SEQ * ESW_SHORTS_PER_BLK * 2)  // 134,217,728
#define EX_UINTS_PER_SLOT (16 * HID)                                   // 8192 = 32 KB
#define EX_BYTES   ((size_t)2 * NGROUPS * EX_UINTS_PER_SLOT * 4)       // 1 MB
#define XCD_BYTES  1024

typedef short v8s __attribute__((ext_vector_type(8)));   // 8 bf16 MFMA A/B frag
typedef float v4f __attribute__((ext_vector_type(4)));   // MFMA C/D frag

static __device__ __forceinline__ unsigned short bf_bits(__hip_bfloat16 h) {
    union { __hip_bfloat16 b; unsigned short u; } c; c.b = h; return c.u;
}
static __device__ __forceinline__ void split_hilo(float v, short& hi, short& lo) {
    const __hip_bfloat16 h = __float2bfloat16(v);
    hi = (short)bf_bits(h);
    lo = (short)bf_bits(__float2bfloat16(v - __bfloat162float(h)));
}
static __device__ __forceinline__ void cvt8_hilo(const float* __restrict__ p,
                                                 v8s& hi, v8s& lo) {
    #pragma unroll
    for (int i = 0; i < 8; ++i) { short h, l; split_hilo(p[i], h, l); hi[i] = h; lo[i] = l; }
}
// fast tanh: 1 - 2/(exp(2x)+1); v_exp_f32-based, ~1e-7 abs err
static __device__ __forceinline__ float tanh_fast(float x) {
    const float z = __expf(2.0f * x);
    return 1.0f - 2.0f / (z + 1.0f);
}

// ---------------------------------------------------------------------------
// Precompute E_sw (unchanged, correctness-proven): per (g,t) the 16 emb rows
// split hi/lo, MFMA A-frag order:
//   short off = plane*4096 + (kk*64 + lane)*8 + i,  lane = m + 16*q',
//   element = emb[X[g*16+m][t]][kk*32 + q'*8 + i]
// ---------------------------------------------------------------------------
__global__ __launch_bounds__(256) void esw_build(
    const int* __restrict__ X, const float* __restrict__ emb,
    short* __restrict__ Esw)
{
    const int bid = blockIdx.x;           // g*512 + t
    const int g = bid >> 9, t = bid & 511;
    short* base = Esw + (size_t)bid * ESW_SHORTS_PER_BLK;
    #pragma unroll
    for (int h = 0; h < 2; ++h) {
        const int f    = threadIdx.x + h * 256;   // frag id 0..511
        const int kk   = f >> 6, lane = f & 63;
        const int m    = lane & 15, qp = lane >> 4;
        const int idx  = X[(g * 16 + m) * L_SEQ + t];
        const float* src = emb + (size_t)idx * EMB_D + kk * 32 + qp * 8;
        v8s hi8, lo8;
        cvt8_hilo(src, hi8, lo8);
        short* d = base + (size_t)(kk * 64 + lane) * 8;
        *(v8s*)d          = hi8;
        *(v8s*)(d + 4096) = lo8;
    }
}

// ---------------------------------------------------------------------------
// Persistent RNN scan: R11 skeleton (cooperative h staging -> LDS broadcast,
// ONE barrier/step, per-word seqlock epoch tags, no flags/drains) + runtime
// XCD-verified L2-LOCAL exchange fast path:
//   All 8 members of a group land on one XCD under round-robin dispatch
//   (bids g, g+16, ..., g+112 are all == g mod 8). Verified at runtime via
//   s_getreg(HW_REG_XCC_ID) exchange. If same XCD: publish = PLAIN stores
//   (write-through to the shared XCD L2 = intra-XCD coherence point), poll =
//   sc0 loads (bypass L1, hit L2) — ~200cyc RTT vs ~650 for the sc1/L3 path.
//   If not: R11's sc1 path (correctness never depends on placement).
// R12 lesson baked in: slot crosses the fabric ONCE per wg (cooperative,
// coalesced 16 u64/thread), never once per wave.
// E frags: direct cached register loads from Esw (plain, coalesced 1KB/instr).
// ---------------------------------------------------------------------------
__global__ __launch_bounds__(256, 1) void rnn_scan7(
    const float* __restrict__ Whh,
    const float* __restrict__ Whh_b,
    const float* __restrict__ Wxh,
    const float* __restrict__ Wxh_b,
    const short* __restrict__ Esw,
    unsigned int* __restrict__ ex,
    int* __restrict__ xcdws,
    float* __restrict__ out)
{
    const int bid  = blockIdx.x;
    const int g    = bid & 15;    // group
    const int j    = bid >> 4;    // member 0..7
    const int tid  = threadIdx.x;
    const int w    = tid >> 6;
    const int l    = tid & 63;
    const int lo16 = l & 15;
    const int q    = l >> 4;
    const int cbase = j * 64 + w * 16;
    const int nbase = g * 16;

    // LDS: h parity dbuf [P][plane][4096 u32] = 64 KB + 4 KB transpose scratch
    __shared__ unsigned int hbuf[2][2][4096];
    __shared__ unsigned int tp[4][256];

    // Whh 64-col slice as hi/lo bf16 B-frags (128 VGPRs)
    v8s bhi[16], blo[16];
    {
        const float* wp = Whh + (long)(cbase + lo16) * HID + q * 8;
        #pragma unroll
        for (int kk = 0; kk < 16; ++kk) cvt8_hilo(wp + kk * 32, bhi[kk], blo[kk]);
    }
    // Wxh 64-col slice (64 VGPRs)
    v8s xhi[8], xlo[8];
    {
        const float* wp = Wxh + (long)(cbase + lo16) * EMB_D + q * 8;
        #pragma unroll
        for (int kk = 0; kk < 8; ++kk) cvt8_hilo(wp + kk * 32, xhi[kk], xlo[kk]);
    }
    const int hcol = cbase + lo16;
    const float bias = Whh_b[hcol] + Wxh_b[hcol];

    // wave's contiguous 1 KB publish region (uints): kk_s = 2j + (w>>1),
    // covering q2 = 2(w&1)..2(w&1)+1.
    const int region = (2 * j + (w >> 1)) * 512 + (w & 1) * 256;

    unsigned int* ex0 = ex + (size_t)g * EX_UINTS_PER_SLOT;              // parity 0
    unsigned int* ex1 = ex + (size_t)(NGROUPS + g) * EX_UINTS_PER_SLOT;  // parity 1
    const short* esrc = Esw + (size_t)(g * 512) * ESW_SHORTS_PER_BLK;

    // ---- runtime XCD check: fast path iff all 8 members share an XCD ----
    unsigned int xcd;
    asm volatile("s_getreg_b32 %0, hwreg(HW_REG_XCC_ID)" : "=s"(xcd));
    int* xbuf = xcdws + g * 8;
    if (tid == 0)
        __hip_atomic_store(&xbuf[j], (int)(xcd | 256),
                           __ATOMIC_RELAXED, __HIP_MEMORY_SCOPE_AGENT);
    bool fastp = true;
    {
        int vals[8]; bool ready;
        do {
            ready = true;
            #pragma unroll
            for (int k = 0; k < 8; ++k) {
                vals[k] = __hip_atomic_load(&xbuf[k], __ATOMIC_RELAXED,
                                            __HIP_MEMORY_SCOPE_AGENT);
                ready = ready && ((vals[k] & 256) != 0);
            }
        } while (!ready);
        #pragma unroll
        for (int k = 1; k < 8; ++k) fastp = fastp && (vals[k] == vals[0]);
    }

    for (int t = 0; t < L_SEQ; ++t) {
        const int P = t & 1;
        const unsigned long long* exsrc =
            (const unsigned long long*)(P ? ex1 : ex0);
        unsigned int* exdst = P ? ex0 : ex1;

        // (1) E frags: 16 plain cached dwordx4 loads + 24 E MFMAs (fills the
        //     slack while peers' h propagates; loads coalesce 1 KB/instr).
        v4f acc0 = {0,0,0,0}, acc1 = {0,0,0,0}, acc2 = {0,0,0,0};
        {
            const short* eb = esrc + (size_t)t * ESW_SHORTS_PER_BLK;
            #pragma unroll
            for (int kk = 0; kk < 8; ++kk) {
                v8s ah = *(const v8s*)(eb + (kk * 64 + l) * 8);
                v8s al = *(const v8s*)(eb + 4096 + (kk * 64 + l) * 8);
                acc0 = __builtin_amdgcn_mfma_f32_16x16x32_bf16(ah, xhi[kk], acc0, 0, 0, 0);
                acc1 = __builtin_amdgcn_mfma_f32_16x16x32_bf16(ah, xlo[kk], acc1, 0, 0, 0);
                acc2 = __builtin_amdgcn_mfma_f32_16x16x32_bf16(al, xhi[kk], acc2, 0, 0, 0);
            }
        }

        // (2) seqlock poll, cooperative (16 u64/thread, fully coalesced)
        unsigned long long hv[16];
        const unsigned long long M = 0x0001000000010000ull;
        const unsigned long long want = ((t >> 1) & 1) ? M : 0ull;
        if (fastp) {
            // L2-local: monolithic asm = 16 sc0 loads + vmcnt(0); outputs are
            // early-clobber so no use-before-wait hazard exists.
            const unsigned long long* pb = exsrc + tid;
            bool pass;
            do {
                asm volatile(
                    "global_load_dwordx2 %[o0],  %[a0], off sc0\n\t"
                    "global_load_dwordx2 %[o1],  %[a0], off offset:2048 sc0\n\t"
                    "global_load_dwordx2 %[o2],  %[a1], off sc0\n\t"
                    "global_load_dwordx2 %[o3],  %[a1], off offset:2048 sc0\n\t"
                    "global_load_dwordx2 %[o4],  %[a2], off sc0\n\t"
                    "global_load_dwordx2 %[o5],  %[a2], off offset:2048 sc0\n\t"
                    "global_load_dwordx2 %[o6],  %[a3], off sc0\n\t"
                    "global_load_dwordx2 %[o7],  %[a3], off offset:2048 sc0\n\t"
                    "global_load_dwordx2 %[o8],  %[a4], off sc0\n\t"
                    "global_load_dwordx2 %[o9],  %[a4], off offset:2048 sc0\n\t"
                    "global_load_dwordx2 %[o10], %[a5], off sc0\n\t"
                    "global_load_dwordx2 %[o11], %[a5], off offset:2048 sc0\n\t"
                    "global_load_dwordx2 %[o12], %[a6], off sc0\n\t"
                    "global_load_dwordx2 %[o13], %[a6], off offset:2048 sc0\n\t"
                    "global_load_dwordx2 %[o14], %[a7], off sc0\n\t"
                    "global_load_dwordx2 %[o15], %[a7], off offset:2048 sc0\n\t"
                    "s_waitcnt vmcnt(0)"
                    : [o0]"=&v"(hv[0]),  [o1]"=&v"(hv[1]),  [o2]"=&v"(hv[2]),
                      [o3]"=&v"(hv[3]),  [o4]"=&v"(hv[4]),  [o5]"=&v"(hv[5]),
                      [o6]"=&v"(hv[6]),  [o7]"=&v"(hv[7]),  [o8]"=&v"(hv[8]),
                      [o9]"=&v"(hv[9]),  [o10]"=&v"(hv[10]),[o11]"=&v"(hv[11]),
                      [o12]"=&v"(hv[12]),[o13]"=&v"(hv[13]),[o14]"=&v"(hv[14]),
                      [o15]"=&v"(hv[15])
                    : [a0]"v"(pb),        [a1]"v"(pb + 512),
                      [a2]"v"(pb + 1024), [a3]"v"(pb + 1536),
                      [a4]"v"(pb + 2048), [a5]"v"(pb + 2560),
                      [a6]"v"(pb + 3072), [a7]"v"(pb + 3584)
                    : "memory");
                unsigned long long x = 0;
                #pragma unroll
                for (int s = 0; s < 16; ++s) x |= (hv[s] ^ want);
                pass = ((x & M) == 0ull);
            } while (!__all(pass));
        } else {
            // agent/L3 fallback (R11-proven)
            bool pass;
            do {
                #pragma unroll
                for (int s = 0; s < 16; ++s)
                    hv[s] = __hip_atomic_load(exsrc + s * 256 + tid,
                                              __ATOMIC_RELAXED,
                                              __HIP_MEMORY_SCOPE_AGENT);
                unsigned long long x = 0;
                #pragma unroll
                for (int s = 0; s < 16; ++s) x |= (hv[s] ^ want);
                pass = ((x & M) == 0ull);
            } while (!__all(pass));
        }

        // (3) unpack -> LDS planes (lane stride 1 u32: conflict-free)
        #pragma unroll
        for (int s = 0; s < 16; ++s) {
            const int o = s * 256 + tid;
            const unsigned int w0 = (unsigned int)hv[s];
            const unsigned int w1 = (unsigned int)(hv[s] >> 32);
            hbuf[P][0][o] = (w0 & 0xffffu) | (w1 << 16);
            hbuf[P][1][o] = (w0 >> 16)     | (w1 & 0xffff0000u);
        }
        __syncthreads();   // the step's ONLY barrier: h LDS broadcast ready

        // (4) h MFMAs (K=512) from LDS frags (2-lane/bank pattern = free)
        {
            const short* lh = (const short*)&hbuf[P][0][0];
            #pragma unroll
            for (int kk = 0; kk < 16; ++kk) {
                v8s ah = *(const v8s*)(lh + (kk * 64 + l) * 8);
                v8s al = *(const v8s*)(lh + 8192 + (kk * 64 + l) * 8);
                acc0 = __builtin_amdgcn_mfma_f32_16x16x32_bf16(ah, bhi[kk], acc0, 0, 0, 0);
                acc1 = __builtin_amdgcn_mfma_f32_16x16x32_bf16(ah, blo[kk], acc1, 0, 0, 0);
                acc2 = __builtin_amdgcn_mfma_f32_16x16x32_bf16(al, bhi[kk], acc2, 0, 0, 0);
            }
        }

        // (5) epilogue: tanh, split, tag bit16, transpose via wave-local LDS,
        //     4 coalesced publish stores. No drain, no flag, no barrier.
        if (t < L_SEQ - 1) {
            const unsigned int wtag = (unsigned int)(((t + 1) >> 1) & 1) << 16;
            unsigned int* myt = tp[w];
            #pragma unroll
            for (int r = 0; r < 4; ++r) {
                const int m = q * 4 + r;             // C/D: row=(lane>>4)*4+r
                const float pre = acc0[r] + acc1[r] + acc2[r] + bias;
                const float hh = tanh_fast(pre);
                short hi, lo; split_hilo(hh, hi, lo);
                unsigned int word = (unsigned int)(unsigned short)hi
                                  | ((unsigned int)(unsigned short)lo << 16);
                word = (word & 0xFFFEFFFFu) | wtag;   // lo-LSB := epoch tag
                myt[(m + 16 * (lo16 >> 3)) * 8 + (lo16 & 7)] = word;
            }
            asm volatile("s_waitcnt lgkmcnt(0)" ::: "memory");
            if (fastp) {
                #pragma unroll
                for (int k = 0; k < 4; ++k) {
                    unsigned int* p = exdst + region + k * 64 + l;
                    const unsigned int val = myt[k * 64 + l];
                    // plain store: write-through to the shared XCD L2
                    asm volatile("global_store_dword %[a], %[d], off"
                                 :: [a]"v"(p), [d]"v"(val) : "memory");
                }
            } else {
                #pragma unroll
                for (int k = 0; k < 4; ++k) {
                    const unsigned int val = myt[k * 64 + l];
                    __hip_atomic_store(exdst + region + k * 64 + l, val,
                                       __ATOMIC_RELAXED, __HIP_MEMORY_SCOPE_AGENT);
                }
            }
        } else {
            #pragma unroll
            for (int r = 0; r < 4; ++r) {
                const int m = q * 4 + r;
                const float pre = acc0[r] + acc1[r] + acc2[r] + bias;
                out[(long)(nbase + m) * HID + hcol] = tanh_fast(pre);
            }
        }
    }
}

// ---------------------------------------------------------------------------
extern "C" void kernel_launch(void* const* d_in, const int* in_sizes, int n_in,
                              void* d_out, int out_size, void* d_ws, size_t ws_size,
                              hipStream_t stream) {
    const int*   X     = (const int*)d_in[0];
    const float* emb   = (const float*)d_in[1];
    const float* Whh   = (const float*)d_in[2];
    const float* Whh_b = (const float*)d_in[3];
    const float* Wxh   = (const float*)d_in[4];
    const float* Wxh_b = (const float*)d_in[5];

    char* ws = (char*)d_ws;
    short*        Esw   = (short*)ws;
    unsigned int* ex    = (unsigned int*)(ws + ESW_BYTES);
    int*          xcdws = (int*)(ws + ESW_BYTES + EX_BYTES);

    // parity 0 := 0x00 (h(0)=0, tag 0 matches t=0 immediately);
    // parity 1 := 0xFF (tag 1 blocks t=1 until step-0 data lands);
    // xcd scratch := 0 (bit8 clear = not yet published).
    hipMemsetAsync(ex, 0x00, EX_BYTES / 2, stream);
    hipMemsetAsync((char*)ex + EX_BYTES / 2, 0xFF, EX_BYTES / 2, stream);
    hipMemsetAsync(xcdws, 0x00, XCD_BYTES, stream);

    esw_build<<<dim3(NGROUPS * L_SEQ), dim3(256), 0, stream>>>(X, emb, Esw);
    rnn_scan7<<<dim3(NGROUPS * GWGS), dim3(256), 0, stream>>>(
        Whh, Whh_b, Wxh, Wxh_b, Esw, ex, xcdws, (float*)d_out);
}